// Round 8
// baseline (420.138 us; speedup 1.0000x reference)
//
#include <hip/hip_runtime.h>
#include <math.h>

// Problem constants
#define BATCH 65536
#define XD 362
#define ZD 100

// ws layout (bytes):
//   [0,256)               : counts[3] (int), zeroed each launch
//   [256, 786688)         : idxlist[3][65536] (int)
//   [786688, +4308992)    : repacked bf16 weights in MFMA B-fragment order
#define WS_IDX_OFF 256
#define WS_WT_OFF  786688

// Weight offsets in bf16 elements. Fragment order: for each matrix,
// index = ((ct*NKT + kt)*64 + lane)*8 + j, where the fragment element is
// B[k = kt*32 + (lane>>4)*8 + j][n = ct*16 + (lane&15)], zero-padded to Kp,Np.
// Np padded to multiples of 128 for the 8-way column split.
#define OFF_W1 0        // Kp=384 Np=256 (98304)
#define OFF_W2 98304    // Kp=256 Np=256 (65536)
#define OFF_W3 163840   // Kp=224 Np=128 (28672)
#define OFF_E1 192512   // 3 x Kp=128 Np=256, stride 32768
#define OFF_E2 290816   // 3 x Kp=160 Np=256, stride 40960
#define OFF_E3 413696   // 3 x Kp=256 Np=384, stride 98304
#define OFF_E4 708608   // 3 x Kp=320 Np=384, stride 122880

#define ROWS 48  // rows per block (RT=3 row-tiles of 16)

typedef short short8 __attribute__((ext_vector_type(8)));
typedef float f32x4 __attribute__((ext_vector_type(4)));

__device__ __forceinline__ unsigned short f2bf(float f) {
    union { float f; unsigned u; } v; v.f = f;
    unsigned u = v.u + 0x7fffu + ((v.u >> 16) & 1u);  // RNE
    return (unsigned short)(u >> 16);
}
__device__ __forceinline__ float bf2f(unsigned u) {
    union { unsigned u; float f; } v; v.u = u << 16; return v.f;
}

// ---------------- repack: W[K][N] fp32 -> bf16 MFMA B-fragment order --------
__global__ __launch_bounds__(256) void repack_kernel(
    const float* __restrict__ W1, const float* __restrict__ W2,
    const float* __restrict__ W3, const float* __restrict__ eW1,
    const float* __restrict__ eW2, const float* __restrict__ eW3,
    const float* __restrict__ eW4, unsigned short* __restrict__ dst) {
    int m = blockIdx.y;
    const float* src; int K, N, Kp, Np; size_t off;
    if (m == 0)      { src = W1; K = 362; N = 256; Kp = 384; Np = 256; off = OFF_W1; }
    else if (m == 1) { src = W2; K = 256; N = 200; Kp = 256; Np = 256; off = OFF_W2; }
    else if (m == 2) { src = W3; K = 200; N = 100; Kp = 224; Np = 128; off = OFF_W3; }
    else if (m <= 5) { int e = m - 3;  src = eW1 + e * 15000;  K = 100; N = 150; Kp = 128; Np = 256; off = OFF_E1 + (size_t)e * 32768; }
    else if (m <= 8) { int e = m - 6;  src = eW2 + e * 37500;  K = 150; N = 250; Kp = 160; Np = 256; off = OFF_E2 + (size_t)e * 40960; }
    else if (m <= 11){ int e = m - 9;  src = eW3 + e * 75000;  K = 250; N = 300; Kp = 256; Np = 384; off = OFF_E3 + (size_t)e * 98304; }
    else             { int e = m - 12; src = eW4 + e * 108600; K = 300; N = 362; Kp = 320; Np = 384; off = OFF_E4 + (size_t)e * 122880; }
    int nkt = Kp / 32;
    int total = Kp * Np;
    for (int i = blockIdx.x * 256 + threadIdx.x; i < total; i += gridDim.x * 256) {
        int j = i & 7, lane = (i >> 3) & 63, t = i >> 9;
        int kt = t % nkt, ct = t / nkt;
        int k = kt * 32 + (lane >> 4) * 8 + j;
        int n = ct * 16 + (lane & 15);
        float v = (k < K && n < N) ? src[(size_t)k * N + n] : 0.0f;
        dst[off + i] = f2bf(v);
    }
}

// ---------------- bucket rows by expert (wave-aggregated atomics) -----------
__global__ __launch_bounds__(256) void bucket_kernel(const int* __restrict__ a,
                                                     int* __restrict__ counts,
                                                     int* __restrict__ idxlist) {
    int b = blockIdx.x * 256 + threadIdx.x;
    int lane = threadIdx.x & 63;
    int e = a[b];
    unsigned long long below = (lane == 63) ? ~0ull >> 1
                                            : ((1ull << (lane + 1)) - 1ull) >> 1;
    int pos = 0;
#pragma unroll
    for (int ee = 0; ee < 3; ++ee) {
        unsigned long long mask = __ballot(e == ee);
        if (e == ee) {
            int leader = __ffsll((long long)mask) - 1;
            int base = 0;
            if (lane == leader)
                base = atomicAdd(&counts[ee], __popcll(mask));
            base = __shfl(base, leader, 64);
            pos = base + __popcll(mask & below);
        }
    }
    idxlist[e * BATCH + pos] = b;
}

// MFMA layer over a 48-row LDS tile, 8-wave column split, RT=3 row-tiles.
// in: bf16 LDS [48][LDI] (zero-padded to KP). out: bf16 LDS [48][LDO],
// relu(acc+bias), cols n<NSTORE written, zeros for NREAL<=n<NSTORE.
// Wave wv owns col-tiles {wv, wv+8, ...}; each B-fragment feeds 3 MFMAs
// (row-tiles 0..2) -> 3x MFMA per L2 fragment load vs 16-row blocks.
// A-frag: [m=lane&15][k=quad*8+j]; C/D: row=quad*4+reg, col=lane&15.
template <int KP, int NP, int LDI, int LDO, int NREAL, int NSTORE>
__device__ __forceinline__ void mfma_layer(
    const unsigned short* __restrict__ Wf, const float* __restrict__ bias,
    const unsigned short* __restrict__ inL, unsigned short* __restrict__ outL,
    int wv, int lane) {
    constexpr int NKT = KP / 32, NCT = NP / 16, CPW = NCT / 8;
    const int quad = lane >> 4, l15 = lane & 15;
    f32x4 acc[3][CPW];
#pragma unroll
    for (int rt = 0; rt < 3; ++rt)
#pragma unroll
        for (int i = 0; i < CPW; ++i) acc[rt][i] = (f32x4){0.f, 0.f, 0.f, 0.f};
    const unsigned short* ap = inL + l15 * LDI + quad * 8;
    __builtin_amdgcn_s_setprio(1);
#pragma unroll
    for (int kt = 0; kt < NKT; ++kt) {
        short8 a0 = *(const short8*)(ap + kt * 32);
        short8 a1 = *(const short8*)(ap + 16 * LDI + kt * 32);
        short8 a2 = *(const short8*)(ap + 32 * LDI + kt * 32);
        short8 bf[CPW];
#pragma unroll
        for (int i = 0; i < CPW; ++i)
            bf[i] = *(const short8*)(Wf + ((size_t)((wv + 8 * i) * NKT + kt) * 64 + lane) * 8);
#pragma unroll
        for (int i = 0; i < CPW; ++i) {
            acc[0][i] = __builtin_amdgcn_mfma_f32_16x16x32_bf16(a0, bf[i], acc[0][i], 0, 0, 0);
            acc[1][i] = __builtin_amdgcn_mfma_f32_16x16x32_bf16(a1, bf[i], acc[1][i], 0, 0, 0);
            acc[2][i] = __builtin_amdgcn_mfma_f32_16x16x32_bf16(a2, bf[i], acc[2][i], 0, 0, 0);
        }
    }
    __builtin_amdgcn_s_setprio(0);
#pragma unroll
    for (int i = 0; i < CPW; ++i) {
        int n = (wv + 8 * i) * 16 + l15;
        if (n < NSTORE) {
            float bv = (n < NREAL) ? bias[n] : 0.f;
#pragma unroll
            for (int rt = 0; rt < 3; ++rt)
#pragma unroll
                for (int r = 0; r < 4; ++r) {
                    int row = rt * 16 + quad * 4 + r;
                    float v = fmaxf(acc[rt][i][r] + bv, 0.f);
                    outL[row * LDO + n] = (n < NREAL) ? f2bf(v) : (unsigned short)0;
                }
        }
    }
}

// ------- fused encoder + expert chain + loss over bucketed rows, 48/block ---
// Two-buffer ping-pong (loss epilogue reads x/xn directly — L3-resident):
//   A (48x392): x -> h2 -> eh1 -> eh3 ;  B (48x264): h1 -> z -> eh2
// 512 threads = 8 waves, column-split 8-way, RT=3 row-tiles per wave.
// LDS ~63 KB -> 2 blocks/CU (16 waves); s_setprio(1) around MFMA clusters
// (co-resident blocks sit at different phases -> scheduler can favor MFMA).
__global__ __launch_bounds__(512, 4) void fused_kernel(
    const float* __restrict__ x, const float* __restrict__ xn,
    const int* __restrict__ counts, const int* __restrict__ idxlist,
    const unsigned short* __restrict__ Wts,
    const float* __restrict__ b1, const float* __restrict__ b2,
    const float* __restrict__ b3, const float* __restrict__ eb1,
    const float* __restrict__ eb2, const float* __restrict__ eb3,
    const float* __restrict__ eb4, float* __restrict__ out) {
    int e = blockIdx.y;
    int cnt = counts[e];
    int start = blockIdx.x * ROWS;
    if (start >= cnt) return;
    int nrows = min(ROWS, cnt - start);

    __shared__ unsigned short A[ROWS * 392];
    __shared__ unsigned short B[ROWS * 264];
    __shared__ int s_idx[ROWS];
    __shared__ float s_part[8];

    int tid = threadIdx.x;
    int wv = tid >> 6, lane = tid & 63;
    const int quad = lane >> 4, l15 = lane & 15;

    if (tid < ROWS)
        s_idx[tid] = (tid < nrows) ? idxlist[e * BATCH + start + tid] : -1;
    __syncthreads();

    // stage gathered x rows -> A bf16 ld392 (196 dwords/row), zero pad k>=362
    {
        unsigned* dA = (unsigned*)A;
        for (int i = tid; i < ROWS * 196; i += 512) {
            int r = i / 196, c = i - r * 196;
            int b = s_idx[r];
            unsigned pk = 0u;
            if (c < 181 && b >= 0) {
                float2 v = *(const float2*)(x + (size_t)b * 362 + 2 * c);
                pk = (unsigned)f2bf(v.x) | ((unsigned)f2bf(v.y) << 16);
            }
            dA[i] = pk;
        }
    }
    __syncthreads();
    // enc L1: x(Kp384, A ld392) -> h1 (B ld264)
    mfma_layer<384, 256, 392, 264, 256, 256>(Wts + OFF_W1, b1, A, B, wv, lane);
    __syncthreads();
    // enc L2: h1(Kp256, B ld264) -> h2 (A ld264 region, 200 real pad 224)
    mfma_layer<256, 256, 264, 264, 200, 224>(Wts + OFF_W2, b2, B, A, wv, lane);
    __syncthreads();
    // enc L3: h2(Kp224, A ld264) -> z (B ld136, 100 real sigmoid, pad 128)
    // CPW=1 (Np=128, 8 waves): ct = wv.
    {
        const unsigned short* W3f = Wts + OFF_W3;
        f32x4 acc3[3];
#pragma unroll
        for (int rt = 0; rt < 3; ++rt) acc3[rt] = (f32x4){0.f, 0.f, 0.f, 0.f};
        const unsigned short* ap = A + l15 * 264 + quad * 8;
        __builtin_amdgcn_s_setprio(1);
#pragma unroll
        for (int kt = 0; kt < 7; ++kt) {
            short8 a0 = *(const short8*)(ap + kt * 32);
            short8 a1 = *(const short8*)(ap + 16 * 264 + kt * 32);
            short8 a2 = *(const short8*)(ap + 32 * 264 + kt * 32);
            short8 bf = *(const short8*)(W3f + ((size_t)(wv * 7 + kt) * 64 + lane) * 8);
            acc3[0] = __builtin_amdgcn_mfma_f32_16x16x32_bf16(a0, bf, acc3[0], 0, 0, 0);
            acc3[1] = __builtin_amdgcn_mfma_f32_16x16x32_bf16(a1, bf, acc3[1], 0, 0, 0);
            acc3[2] = __builtin_amdgcn_mfma_f32_16x16x32_bf16(a2, bf, acc3[2], 0, 0, 0);
        }
        __builtin_amdgcn_s_setprio(0);
        int n = wv * 16 + l15;  // 0..127
        float bv = (n < 100) ? b3[n] : 0.f;
#pragma unroll
        for (int rt = 0; rt < 3; ++rt)
#pragma unroll
            for (int r = 0; r < 4; ++r) {
                int row = rt * 16 + quad * 4 + r;
                float s = 1.0f / (1.0f + expf(-(acc3[rt][r] + bv)));
                B[row * 136 + n] = (n < 100) ? f2bf(s) : (unsigned short)0;
            }
    }
    __syncthreads();
    // E1: z(Kp128, B ld136) -> eh1 (A ld168, 150 real pad 160)
    mfma_layer<128, 256, 136, 168, 150, 160>(Wts + OFF_E1 + (size_t)e * 32768,
                                             eb1 + e * 150, B, A, wv, lane);
    __syncthreads();
    // E2: eh1(Kp160, A ld168) -> eh2 (B ld264, 250 real pad 256)
    mfma_layer<160, 256, 168, 264, 250, 256>(Wts + OFF_E2 + (size_t)e * 40960,
                                             eb2 + e * 250, A, B, wv, lane);
    __syncthreads();
    // E3: eh2(Kp256, B ld264) -> eh3 (A ld328, 300 real pad 320)
    mfma_layer<256, 384, 264, 328, 300, 320>(Wts + OFF_E3 + (size_t)e * 98304,
                                             eb3 + e * 300, B, A, wv, lane);
    __syncthreads();

    // E4: eh3(Kp320, A ld328), Np=384 (CPW=3), loss vs (xn-x) read directly
    float lacc = 0.0f;
    {
        constexpr int NKT = 10, CPW = 3;
        const unsigned short* Wf = Wts + OFF_E4 + (size_t)e * 122880;
        const float* bias4 = eb4 + (size_t)e * 362;
        f32x4 acc[3][CPW];
#pragma unroll
        for (int rt = 0; rt < 3; ++rt)
#pragma unroll
            for (int i = 0; i < CPW; ++i) acc[rt][i] = (f32x4){0.f, 0.f, 0.f, 0.f};
        const unsigned short* ap = A + l15 * 328 + quad * 8;
        __builtin_amdgcn_s_setprio(1);
#pragma unroll
        for (int kt = 0; kt < NKT; ++kt) {
            short8 a0 = *(const short8*)(ap + kt * 32);
            short8 a1 = *(const short8*)(ap + 16 * 328 + kt * 32);
            short8 a2 = *(const short8*)(ap + 32 * 328 + kt * 32);
            short8 bf[CPW];
#pragma unroll
            for (int i = 0; i < CPW; ++i)
                bf[i] = *(const short8*)(Wf + ((size_t)((wv + 8 * i) * NKT + kt) * 64 + lane) * 8);
#pragma unroll
            for (int i = 0; i < CPW; ++i) {
                acc[0][i] = __builtin_amdgcn_mfma_f32_16x16x32_bf16(a0, bf[i], acc[0][i], 0, 0, 0);
                acc[1][i] = __builtin_amdgcn_mfma_f32_16x16x32_bf16(a1, bf[i], acc[1][i], 0, 0, 0);
                acc[2][i] = __builtin_amdgcn_mfma_f32_16x16x32_bf16(a2, bf[i], acc[2][i], 0, 0, 0);
            }
        }
        __builtin_amdgcn_s_setprio(0);
        const float WC0 = 1.0f / 65536.0f;
        const float WCR = 1.0f / (361.0f * 65536.0f);
        // loss epilogue: scattered-but-64B-coalesced x/xn reads per 16-lane
        // group, consumed immediately (transient — no cross-MFMA live range).
#pragma unroll
        for (int i = 0; i < CPW; ++i) {
            int n = (wv + 8 * i) * 16 + l15;
            if (n < 362) {
                float bv = bias4[n];
                float wgt = (n == 0) ? WC0 : WCR;
#pragma unroll
                for (int rt = 0; rt < 3; ++rt)
#pragma unroll
                    for (int r = 0; r < 4; ++r) {
                        int row = rt * 16 + quad * 4 + r;
                        int b = s_idx[row];
                        if (b >= 0) {
                            size_t o = (size_t)b * 362 + n;
                            float delta = xn[o] - x[o];
                            float err = acc[rt][i][r] + bv - delta;
                            lacc += wgt * err * err;
                        }
                    }
            }
        }
    }
    // block reduction -> atomicAdd
    for (int off = 32; off; off >>= 1)
        lacc += __shfl_down(lacc, off, 64);
    if ((tid & 63) == 0) s_part[wv] = lacc;
    __syncthreads();
    if (tid == 0) {
        float s = 0.f;
#pragma unroll
        for (int i = 0; i < 8; ++i) s += s_part[i];
        atomicAdd(out, s);
    }
}

extern "C" void kernel_launch(void* const* d_in, const int* in_sizes, int n_in,
                              void* d_out, int out_size, void* d_ws, size_t ws_size,
                              hipStream_t stream) {
    const float* x   = (const float*)d_in[0];
    const float* xn  = (const float*)d_in[1];
    const int*   a   = (const int*)d_in[2];
    const float* W1  = (const float*)d_in[3];
    const float* b1  = (const float*)d_in[4];
    const float* W2  = (const float*)d_in[5];
    const float* b2  = (const float*)d_in[6];
    const float* W3  = (const float*)d_in[7];
    const float* b3  = (const float*)d_in[8];
    const float* eW1 = (const float*)d_in[9];
    const float* eb1 = (const float*)d_in[10];
    const float* eW2 = (const float*)d_in[11];
    const float* eb2 = (const float*)d_in[12];
    const float* eW3 = (const float*)d_in[13];
    const float* eb3 = (const float*)d_in[14];
    const float* eW4 = (const float*)d_in[15];
    const float* eb4 = (const float*)d_in[16];

    char* ws = (char*)d_ws;
    int* counts           = (int*)ws;
    int* idxlist          = (int*)(ws + WS_IDX_OFF);
    unsigned short* Wts   = (unsigned short*)(ws + WS_WT_OFF);

    hipMemsetAsync(counts, 0, 256, stream);
    hipMemsetAsync(d_out, 0, sizeof(float), stream);

    repack_kernel<<<dim3(32, 15), 256, 0, stream>>>(W1, W2, W3, eW1, eW2, eW3, eW4, Wts);
    bucket_kernel<<<BATCH / 256, 256, 0, stream>>>(a, counts, idxlist);
    fused_kernel<<<dim3((BATCH + ROWS - 1) / ROWS, 3), 512, 0, stream>>>(
        x, xn, counts, idxlist, Wts, b1, b2, b3, eb1, eb2, eb3, eb4, (float*)d_out);
}

// Round 9
// 400.351 us; speedup vs baseline: 1.0494x; 1.0494x over previous
//
#include <hip/hip_runtime.h>
#include <math.h>

// Problem constants
#define BATCH 65536
#define XD 362
#define ZD 100

// ws layout (bytes):
//   [0,256)               : counts[3] (int), zeroed each launch
//   [256, 786688)         : idxlist[3][65536] (int)
//   [786688, +4308992)    : repacked bf16 weights in MFMA B-fragment order
#define WS_IDX_OFF 256
#define WS_WT_OFF  786688

// Weight offsets in bf16 elements. Fragment order: for each matrix,
// index = ((ct*NKT + kt)*64 + lane)*8 + j, where the fragment element is
// W[k = kt*32 + (lane>>4)*8 + j][n = ct*16 + (lane&15)], zero-padded to Kp,Np.
// Np padded to multiples of 128 for the 8-way column split.
#define OFF_W1 0        // Kp=384 Np=256 (98304)
#define OFF_W2 98304    // Kp=256 Np=256 (65536)
#define OFF_W3 163840   // Kp=224 Np=128 (28672)
#define OFF_E1 192512   // 3 x Kp=128 Np=256, stride 32768
#define OFF_E2 290816   // 3 x Kp=160 Np=256, stride 40960
#define OFF_E3 413696   // 3 x Kp=256 Np=384, stride 98304
#define OFF_E4 708608   // 3 x Kp=320 Np=384, stride 122880

#define ROWS 32  // rows per block (RT=2 row-tiles of 16) — R7 base (best occ)

typedef short short8 __attribute__((ext_vector_type(8)));
typedef float f32x4 __attribute__((ext_vector_type(4)));
typedef unsigned u32x2 __attribute__((ext_vector_type(2)));

__device__ __forceinline__ unsigned short f2bf(float f) {
    union { float f; unsigned u; } v; v.f = f;
    unsigned u = v.u + 0x7fffu + ((v.u >> 16) & 1u);  // RNE
    return (unsigned short)(u >> 16);
}
__device__ __forceinline__ float bf2f(unsigned u) {
    union { unsigned u; float f; } v; v.u = u << 16; return v.f;
}

// ---------------- repack: W[K][N] fp32 -> bf16 MFMA fragment order ----------
__global__ __launch_bounds__(256) void repack_kernel(
    const float* __restrict__ W1, const float* __restrict__ W2,
    const float* __restrict__ W3, const float* __restrict__ eW1,
    const float* __restrict__ eW2, const float* __restrict__ eW3,
    const float* __restrict__ eW4, unsigned short* __restrict__ dst) {
    int m = blockIdx.y;
    const float* src; int K, N, Kp, Np; size_t off;
    if (m == 0)      { src = W1; K = 362; N = 256; Kp = 384; Np = 256; off = OFF_W1; }
    else if (m == 1) { src = W2; K = 256; N = 200; Kp = 256; Np = 256; off = OFF_W2; }
    else if (m == 2) { src = W3; K = 200; N = 100; Kp = 224; Np = 128; off = OFF_W3; }
    else if (m <= 5) { int e = m - 3;  src = eW1 + e * 15000;  K = 100; N = 150; Kp = 128; Np = 256; off = OFF_E1 + (size_t)e * 32768; }
    else if (m <= 8) { int e = m - 6;  src = eW2 + e * 37500;  K = 150; N = 250; Kp = 160; Np = 256; off = OFF_E2 + (size_t)e * 40960; }
    else if (m <= 11){ int e = m - 9;  src = eW3 + e * 75000;  K = 250; N = 300; Kp = 256; Np = 384; off = OFF_E3 + (size_t)e * 98304; }
    else             { int e = m - 12; src = eW4 + e * 108600; K = 300; N = 362; Kp = 320; Np = 384; off = OFF_E4 + (size_t)e * 122880; }
    int nkt = Kp / 32;
    int total = Kp * Np;
    for (int i = blockIdx.x * 256 + threadIdx.x; i < total; i += gridDim.x * 256) {
        int j = i & 7, lane = (i >> 3) & 63, t = i >> 9;
        int kt = t % nkt, ct = t / nkt;
        int k = kt * 32 + (lane >> 4) * 8 + j;
        int n = ct * 16 + (lane & 15);
        float v = (k < K && n < N) ? src[(size_t)k * N + n] : 0.0f;
        dst[off + i] = f2bf(v);
    }
}

// ---------------- bucket rows by expert (wave-aggregated atomics) -----------
__global__ __launch_bounds__(256) void bucket_kernel(const int* __restrict__ a,
                                                     int* __restrict__ counts,
                                                     int* __restrict__ idxlist) {
    int b = blockIdx.x * 256 + threadIdx.x;
    int lane = threadIdx.x & 63;
    int e = a[b];
    unsigned long long below = (lane == 63) ? ~0ull >> 1
                                            : ((1ull << (lane + 1)) - 1ull) >> 1;
    int pos = 0;
#pragma unroll
    for (int ee = 0; ee < 3; ++ee) {
        unsigned long long mask = __ballot(e == ee);
        if (e == ee) {
            int leader = __ffsll((long long)mask) - 1;
            int base = 0;
            if (lane == leader)
                base = atomicAdd(&counts[ee], __popcll(mask));
            base = __shfl(base, leader, 64);
            pos = base + __popcll(mask & below);
        }
    }
    idxlist[e * BATCH + pos] = b;
}

// MFMA layer, OPERAND-SWAPPED: acc = mfma(Wfrag, Afrag, acc) computes (A*W)^T.
// Lane l then holds: col = l&15 = batch row (within rt tile), rows quad*4+r =
// 4 CONSECUTIVE output features n = nbase..nbase+3, nbase=(wv+8i)*16+quad*4.
// Epilogue: one 8-byte ds_write per (rt,i) instead of 4 scalar b16 writes.
// in: bf16 LDS [32][LDI] (zero-padded to KP). out: bf16 LDS [32][LDO],
// relu(acc+bias); groups with nbase<NSTORE written; zeros for NREAL<=n.
template <int KP, int NP, int LDI, int LDO, int NREAL, int NSTORE>
__device__ __forceinline__ void mfma_layer(
    const unsigned short* __restrict__ Wf, const float* __restrict__ bias,
    const unsigned short* __restrict__ inL, unsigned short* __restrict__ outL,
    int wv, int lane) {
    constexpr int NKT = KP / 32, NCT = NP / 16, CPW = NCT / 8;
    const int quad = lane >> 4, l15 = lane & 15;
    f32x4 acc[2][CPW];
#pragma unroll
    for (int rt = 0; rt < 2; ++rt)
#pragma unroll
        for (int i = 0; i < CPW; ++i) acc[rt][i] = (f32x4){0.f, 0.f, 0.f, 0.f};
    const unsigned short* ap = inL + l15 * LDI + quad * 8;
    __builtin_amdgcn_s_setprio(1);
#pragma unroll
    for (int kt = 0; kt < NKT; ++kt) {
        short8 a0 = *(const short8*)(ap + kt * 32);
        short8 a1 = *(const short8*)(ap + 16 * LDI + kt * 32);
        short8 bf[CPW];
#pragma unroll
        for (int i = 0; i < CPW; ++i)
            bf[i] = *(const short8*)(Wf + ((size_t)((wv + 8 * i) * NKT + kt) * 64 + lane) * 8);
#pragma unroll
        for (int i = 0; i < CPW; ++i) {
            acc[0][i] = __builtin_amdgcn_mfma_f32_16x16x32_bf16(bf[i], a0, acc[0][i], 0, 0, 0);
            acc[1][i] = __builtin_amdgcn_mfma_f32_16x16x32_bf16(bf[i], a1, acc[1][i], 0, 0, 0);
        }
    }
    __builtin_amdgcn_s_setprio(0);
#pragma unroll
    for (int i = 0; i < CPW; ++i) {
        int nbase = (wv + 8 * i) * 16 + quad * 4;
        if (nbase < NSTORE) {  // NSTORE % 4 == 0: group fully in or out
            float bv[4];
#pragma unroll
            for (int r = 0; r < 4; ++r)
                bv[r] = (nbase + r < NREAL) ? bias[nbase + r] : 0.f;
#pragma unroll
            for (int rt = 0; rt < 2; ++rt) {
                int row = rt * 16 + l15;
                unsigned short h[4];
#pragma unroll
                for (int r = 0; r < 4; ++r) {
                    float v = fmaxf(acc[rt][i][r] + bv[r], 0.f);
                    h[r] = (nbase + r < NREAL) ? f2bf(v) : (unsigned short)0;
                }
                u32x2 pk;
                pk[0] = (unsigned)h[0] | ((unsigned)h[1] << 16);
                pk[1] = (unsigned)h[2] | ((unsigned)h[3] << 16);
                *(u32x2*)(outL + row * LDO + nbase) = pk;  // 8B aligned
            }
        }
    }
}

// ------- fused encoder + expert chain + loss over bucketed rows, 32/block ---
// Two-buffer ping-pong: A (32x392): x -> h2 -> eh1 -> eh3
//                       B (32x264): h1 -> z -> eh2
// 512 threads = 8 waves, 8-way column split, RT=2 row-tiles per wave.
__global__ __launch_bounds__(512, 6) void fused_kernel(
    const float* __restrict__ x, const float* __restrict__ xn,
    const int* __restrict__ counts, const int* __restrict__ idxlist,
    const unsigned short* __restrict__ Wts,
    const float* __restrict__ b1, const float* __restrict__ b2,
    const float* __restrict__ b3, const float* __restrict__ eb1,
    const float* __restrict__ eb2, const float* __restrict__ eb3,
    const float* __restrict__ eb4, float* __restrict__ out) {
    int e = blockIdx.y;
    int cnt = counts[e];
    int start = blockIdx.x * ROWS;
    if (start >= cnt) return;
    int nrows = min(ROWS, cnt - start);

    __shared__ unsigned short A[ROWS * 392];
    __shared__ unsigned short B[ROWS * 264];
    __shared__ int s_idx[ROWS];
    __shared__ float s_part[8];

    int tid = threadIdx.x;
    int wv = tid >> 6, lane = tid & 63;
    const int quad = lane >> 4, l15 = lane & 15;

    if (tid < ROWS)
        s_idx[tid] = (tid < nrows) ? idxlist[e * BATCH + start + tid] : -1;
    __syncthreads();

    // stage gathered x rows -> A bf16 ld392 (196 dwords/row), zero pad k>=362
    {
        unsigned* dA = (unsigned*)A;
        for (int i = tid; i < ROWS * 196; i += 512) {
            int r = i / 196, c = i - r * 196;
            int b = s_idx[r];
            unsigned pk = 0u;
            if (c < 181 && b >= 0) {
                float2 v = *(const float2*)(x + (size_t)b * 362 + 2 * c);
                pk = (unsigned)f2bf(v.x) | ((unsigned)f2bf(v.y) << 16);
            }
            dA[i] = pk;
        }
    }
    __syncthreads();
    // enc L1: x(Kp384, A ld392) -> h1 (B ld264)
    mfma_layer<384, 256, 392, 264, 256, 256>(Wts + OFF_W1, b1, A, B, wv, lane);
    __syncthreads();
    // enc L2: h1(Kp256, B ld264) -> h2 (A ld264 region, 200 real pad 224)
    mfma_layer<256, 256, 264, 264, 200, 224>(Wts + OFF_W2, b2, B, A, wv, lane);
    __syncthreads();
    // enc L3: h2(Kp224, A ld264) -> z (B ld136, 100 real sigmoid, pad 128)
    // CPW=1 (Np=128, 8 waves): ct = wv; swapped operands like mfma_layer.
    {
        const unsigned short* W3f = Wts + OFF_W3;
        f32x4 acc3[2];
#pragma unroll
        for (int rt = 0; rt < 2; ++rt) acc3[rt] = (f32x4){0.f, 0.f, 0.f, 0.f};
        const unsigned short* ap = A + l15 * 264 + quad * 8;
        __builtin_amdgcn_s_setprio(1);
#pragma unroll
        for (int kt = 0; kt < 7; ++kt) {
            short8 a0 = *(const short8*)(ap + kt * 32);
            short8 a1 = *(const short8*)(ap + 16 * 264 + kt * 32);
            short8 bf = *(const short8*)(W3f + ((size_t)(wv * 7 + kt) * 64 + lane) * 8);
            acc3[0] = __builtin_amdgcn_mfma_f32_16x16x32_bf16(bf, a0, acc3[0], 0, 0, 0);
            acc3[1] = __builtin_amdgcn_mfma_f32_16x16x32_bf16(bf, a1, acc3[1], 0, 0, 0);
        }
        __builtin_amdgcn_s_setprio(0);
        int nbase = wv * 16 + quad * 4;  // 0..124
        float bv[4];
#pragma unroll
        for (int r = 0; r < 4; ++r)
            bv[r] = (nbase + r < 100) ? b3[nbase + r] : 0.f;
#pragma unroll
        for (int rt = 0; rt < 2; ++rt) {
            int row = rt * 16 + l15;
            unsigned short h[4];
#pragma unroll
            for (int r = 0; r < 4; ++r) {
                float s = 1.0f / (1.0f + expf(-(acc3[rt][r] + bv[r])));
                h[r] = (nbase + r < 100) ? f2bf(s) : (unsigned short)0;
            }
            u32x2 pk;
            pk[0] = (unsigned)h[0] | ((unsigned)h[1] << 16);
            pk[1] = (unsigned)h[2] | ((unsigned)h[3] << 16);
            *(u32x2*)(B + row * 136 + nbase) = pk;
        }
    }
    __syncthreads();
    // E1: z(Kp128, B ld136) -> eh1 (A ld168, 150 real pad 160)
    mfma_layer<128, 256, 136, 168, 150, 160>(Wts + OFF_E1 + (size_t)e * 32768,
                                             eb1 + e * 150, B, A, wv, lane);
    __syncthreads();
    // E2: eh1(Kp160, A ld168) -> eh2 (B ld264, 250 real pad 256)
    mfma_layer<160, 256, 168, 264, 250, 256>(Wts + OFF_E2 + (size_t)e * 40960,
                                             eb2 + e * 250, A, B, wv, lane);
    __syncthreads();
    // E3: eh2(Kp256, B ld264) -> eh3 (A ld328, 300 real pad 320)
    mfma_layer<256, 384, 264, 328, 300, 320>(Wts + OFF_E3 + (size_t)e * 98304,
                                             eb3 + e * 300, B, A, wv, lane);
    __syncthreads();

    // E4: eh3(Kp320, A ld328), Np=384 (CPW=3), loss vs (xn-x) read directly.
    // Swapped: lane holds 4 consecutive n for batch row rt*16+l15 ->
    // x/xn read as aligned float2 pairs (362 even, nbase even).
    float lacc = 0.0f;
    {
        constexpr int NKT = 10, CPW = 3;
        const unsigned short* Wf = Wts + OFF_E4 + (size_t)e * 122880;
        const float* bias4 = eb4 + (size_t)e * 362;
        f32x4 acc[2][CPW];
#pragma unroll
        for (int rt = 0; rt < 2; ++rt)
#pragma unroll
            for (int i = 0; i < CPW; ++i) acc[rt][i] = (f32x4){0.f, 0.f, 0.f, 0.f};
        const unsigned short* ap = A + l15 * 328 + quad * 8;
        __builtin_amdgcn_s_setprio(1);
#pragma unroll
        for (int kt = 0; kt < NKT; ++kt) {
            short8 a0 = *(const short8*)(ap + kt * 32);
            short8 a1 = *(const short8*)(ap + 16 * 328 + kt * 32);
            short8 bf[CPW];
#pragma unroll
            for (int i = 0; i < CPW; ++i)
                bf[i] = *(const short8*)(Wf + ((size_t)((wv + 8 * i) * NKT + kt) * 64 + lane) * 8);
#pragma unroll
            for (int i = 0; i < CPW; ++i) {
                acc[0][i] = __builtin_amdgcn_mfma_f32_16x16x32_bf16(bf[i], a0, acc[0][i], 0, 0, 0);
                acc[1][i] = __builtin_amdgcn_mfma_f32_16x16x32_bf16(bf[i], a1, acc[1][i], 0, 0, 0);
            }
        }
        __builtin_amdgcn_s_setprio(0);
        const float WC0 = 1.0f / 65536.0f;
        const float WCR = 1.0f / (361.0f * 65536.0f);
#pragma unroll
        for (int i = 0; i < CPW; ++i) {
            int nbase = (wv + 8 * i) * 16 + quad * 4;
            if (nbase < 362) {          // nbase multiple of 4 -> nbase <= 360
                bool p1 = nbase + 2 < 362;  // second pair fully valid?
                float bv0 = bias4[nbase], bv1 = bias4[nbase + 1];
                float bv2 = p1 ? bias4[nbase + 2] : 0.f;
                float bv3 = p1 ? bias4[nbase + 3] : 0.f;
                float w0 = (nbase == 0) ? WC0 : WCR;
#pragma unroll
                for (int rt = 0; rt < 2; ++rt) {
                    int b = s_idx[rt * 16 + l15];
                    if (b >= 0) {
                        const float* xp  = x  + (size_t)b * 362 + nbase;
                        const float* xnp = xn + (size_t)b * 362 + nbase;
                        float2 xa  = *(const float2*)xp;
                        float2 xna = *(const float2*)xnp;
                        float e0 = acc[rt][i][0] + bv0 - (xna.x - xa.x);
                        float e1 = acc[rt][i][1] + bv1 - (xna.y - xa.y);
                        lacc += w0 * e0 * e0 + WCR * e1 * e1;
                        if (p1) {
                            float2 xb  = *(const float2*)(xp + 2);
                            float2 xnb = *(const float2*)(xnp + 2);
                            float e2 = acc[rt][i][2] + bv2 - (xnb.x - xb.x);
                            float e3 = acc[rt][i][3] + bv3 - (xnb.y - xb.y);
                            lacc += WCR * (e2 * e2 + e3 * e3);
                        }
                    }
                }
            }
        }
    }
    // block reduction -> atomicAdd
    for (int off = 32; off; off >>= 1)
        lacc += __shfl_down(lacc, off, 64);
    if ((tid & 63) == 0) s_part[wv] = lacc;
    __syncthreads();
    if (tid == 0) {
        float s = 0.f;
#pragma unroll
        for (int i = 0; i < 8; ++i) s += s_part[i];
        atomicAdd(out, s);
    }
}

extern "C" void kernel_launch(void* const* d_in, const int* in_sizes, int n_in,
                              void* d_out, int out_size, void* d_ws, size_t ws_size,
                              hipStream_t stream) {
    const float* x   = (const float*)d_in[0];
    const float* xn  = (const float*)d_in[1];
    const int*   a   = (const int*)d_in[2];
    const float* W1  = (const float*)d_in[3];
    const float* b1  = (const float*)d_in[4];
    const float* W2  = (const float*)d_in[5];
    const float* b2  = (const float*)d_in[6];
    const float* W3  = (const float*)d_in[7];
    const float* b3  = (const float*)d_in[8];
    const float* eW1 = (const float*)d_in[9];
    const float* eb1 = (const float*)d_in[10];
    const float* eW2 = (const float*)d_in[11];
    const float* eb2 = (const float*)d_in[12];
    const float* eW3 = (const float*)d_in[13];
    const float* eb3 = (const float*)d_in[14];
    const float* eW4 = (const float*)d_in[15];
    const float* eb4 = (const float*)d_in[16];

    char* ws = (char*)d_ws;
    int* counts           = (int*)ws;
    int* idxlist          = (int*)(ws + WS_IDX_OFF);
    unsigned short* Wts   = (unsigned short*)(ws + WS_WT_OFF);

    hipMemsetAsync(counts, 0, 256, stream);
    hipMemsetAsync(d_out, 0, sizeof(float), stream);

    repack_kernel<<<dim3(32, 15), 256, 0, stream>>>(W1, W2, W3, eW1, eW2, eW3, eW4, Wts);
    bucket_kernel<<<BATCH / 256, 256, 0, stream>>>(a, counts, idxlist);
    fused_kernel<<<dim3((BATCH + ROWS - 1) / ROWS, 3), 512, 0, stream>>>(
        x, xn, counts, idxlist, Wts, b1, b2, b3, eb1, eb2, eb3, eb4, (float*)d_out);
}

// Round 11
// 358.196 us; speedup vs baseline: 1.1729x; 1.1177x over previous
//
#include <hip/hip_runtime.h>
#include <math.h>

// Problem constants
#define BATCH 65536
#define XD 362
#define ZD 100

// ws layout (bytes):
//   [0,256)               : counts[3] (int), zeroed by repack_kernel
//   [256, 786688)         : idxlist[3][65536] (int)
//   [786688, +4308992)    : repacked bf16 weights in MFMA fragment order
#define WS_IDX_OFF 256
#define WS_WT_OFF  786688

// Weight offsets in bf16 elements. Fragment order: for each matrix,
// index = ((ct*NKT + kt)*64 + lane)*8 + j, where the fragment element is
// W[k = kt*32 + (lane>>4)*8 + j][n = ct*16 + (lane&15)], zero-padded to Kp,Np.
// Np padded to multiples of 128 for the 8-way column split.
#define OFF_W1 0        // Kp=384 Np=256 (98304)
#define OFF_W2 98304    // Kp=256 Np=256 (65536)
#define OFF_W3 163840   // Kp=224 Np=128 (28672)
#define OFF_E1 192512   // 3 x Kp=128 Np=256, stride 32768
#define OFF_E2 290816   // 3 x Kp=160 Np=256, stride 40960
#define OFF_E3 413696   // 3 x Kp=256 Np=384, stride 98304
#define OFF_E4 708608   // 3 x Kp=320 Np=384, stride 122880

#define ROWS 32  // rows per block (RT=2 row-tiles of 16)

typedef short short8 __attribute__((ext_vector_type(8)));
typedef float f32x4 __attribute__((ext_vector_type(4)));
typedef unsigned u32x2 __attribute__((ext_vector_type(2)));

__device__ __forceinline__ unsigned short f2bf(float f) {
    union { float f; unsigned u; } v; v.f = f;
    unsigned u = v.u + 0x7fffu + ((v.u >> 16) & 1u);  // RNE
    return (unsigned short)(u >> 16);
}
__device__ __forceinline__ float bf2f(unsigned u) {
    union { unsigned u; float f; } v; v.u = u << 16; return v.f;
}

// ---------------- repack: W[K][N] fp32 -> bf16 MFMA fragment order ----------
// Templated dims: the %/ by NKT become compile-time magic multiplies.
template <int K, int N, int Kp, int Np>
__device__ __forceinline__ void repack_one(const float* __restrict__ src,
                                           unsigned short* __restrict__ dst,
                                           int start, int stride) {
    constexpr int NKT = Kp / 32;
    constexpr int total = Kp * Np;
    for (int i = start; i < total; i += stride) {
        int j = i & 7, lane = (i >> 3) & 63, t = i >> 9;
        int kt = t % NKT, ct = t / NKT;
        int k = kt * 32 + (lane >> 4) * 8 + j;
        int n = ct * 16 + (lane & 15);
        float v = (k < K && n < N) ? src[(size_t)k * N + n] : 0.0f;
        dst[i] = f2bf(v);
    }
}

__global__ __launch_bounds__(256) void repack_kernel(
    const float* __restrict__ W1, const float* __restrict__ W2,
    const float* __restrict__ W3, const float* __restrict__ eW1,
    const float* __restrict__ eW2, const float* __restrict__ eW3,
    const float* __restrict__ eW4, unsigned short* __restrict__ dst,
    int* __restrict__ counts) {
    int m = blockIdx.y;
    int start = blockIdx.x * 256 + threadIdx.x;
    int stride = gridDim.x * 256;
    // zero bucket counters here (stream-ordered before bucket_kernel)
    if (m == 0 && blockIdx.x == 0 && threadIdx.x < 3) counts[threadIdx.x] = 0;
    switch (m) {
    case 0: repack_one<362, 256, 384, 256>(W1, dst + OFF_W1, start, stride); break;
    case 1: repack_one<256, 200, 256, 256>(W2, dst + OFF_W2, start, stride); break;
    case 2: repack_one<200, 100, 224, 128>(W3, dst + OFF_W3, start, stride); break;
    case 3: case 4: case 5: {
        int e = m - 3;
        repack_one<100, 150, 128, 256>(eW1 + e * 15000, dst + OFF_E1 + (size_t)e * 32768, start, stride);
        break; }
    case 6: case 7: case 8: {
        int e = m - 6;
        repack_one<150, 250, 160, 256>(eW2 + e * 37500, dst + OFF_E2 + (size_t)e * 40960, start, stride);
        break; }
    case 9: case 10: case 11: {
        int e = m - 9;
        repack_one<250, 300, 256, 384>(eW3 + e * 75000, dst + OFF_E3 + (size_t)e * 98304, start, stride);
        break; }
    default: {
        int e = m - 12;
        repack_one<300, 362, 320, 384>(eW4 + e * 108600, dst + OFF_E4 + (size_t)e * 122880, start, stride);
        break; }
    }
}

// ---------------- bucket rows by expert (block-aggregated atomics) ----------
// 1024-thread blocks: wave ballots -> LDS wave counts -> 3 atomics per BLOCK
// (192 total vs 3072 per-wave) -> per-thread position from block/wave prefix.
__global__ __launch_bounds__(1024) void bucket_kernel(const int* __restrict__ a,
                                                      int* __restrict__ counts,
                                                      int* __restrict__ idxlist) {
    __shared__ int wcnt[16][3];
    __shared__ int wbase[16][3];
    __shared__ int bbase[3];
    int tid = threadIdx.x;
    int b = blockIdx.x * 1024 + tid;
    int wv = tid >> 6, lane = tid & 63;
    int e = a[b];
    unsigned long long below = (lane == 63) ? ~0ull >> 1
                                            : ((1ull << (lane + 1)) - 1ull) >> 1;
    int myofs = 0;
#pragma unroll
    for (int ee = 0; ee < 3; ++ee) {
        unsigned long long mk = __ballot(e == ee);
        if (e == ee) myofs = __popcll(mk & below);
        if (lane == 0) wcnt[wv][ee] = __popcll(mk);
    }
    __syncthreads();
    if (tid < 3) {  // one thread per expert: prefix over the 16 waves
        int s = 0;
#pragma unroll
        for (int w = 0; w < 16; ++w) { wbase[w][tid] = s; s += wcnt[w][tid]; }
        bbase[tid] = atomicAdd(&counts[tid], s);
    }
    __syncthreads();
    int pos = bbase[e] + wbase[wv][e] + myofs;
    idxlist[e * BATCH + pos] = b;
}

// MFMA layer, OPERAND-SWAPPED: acc = mfma(Wfrag, Afrag, acc) computes (A*W)^T.
// Lane l then holds: col = l&15 = batch row (within rt tile), rows quad*4+r =
// 4 CONSECUTIVE output features n = nbase..nbase+3, nbase=(wv+8i)*16+quad*4.
// Epilogue: one 8-byte ds_write per (rt,i) instead of 4 scalar b16 writes.
// in: bf16 LDS [32][LDI] (zero-padded to KP). out: bf16 LDS [32][LDO],
// relu(acc+bias); groups with nbase<NSTORE written; zeros for NREAL<=n.
template <int KP, int NP, int LDI, int LDO, int NREAL, int NSTORE>
__device__ __forceinline__ void mfma_layer(
    const unsigned short* __restrict__ Wf, const float* __restrict__ bias,
    const unsigned short* __restrict__ inL, unsigned short* __restrict__ outL,
    int wv, int lane) {
    constexpr int NKT = KP / 32, NCT = NP / 16, CPW = NCT / 8;
    const int quad = lane >> 4, l15 = lane & 15;
    f32x4 acc[2][CPW];
#pragma unroll
    for (int rt = 0; rt < 2; ++rt)
#pragma unroll
        for (int i = 0; i < CPW; ++i) acc[rt][i] = (f32x4){0.f, 0.f, 0.f, 0.f};
    const unsigned short* ap = inL + l15 * LDI + quad * 8;
    __builtin_amdgcn_s_setprio(1);
#pragma unroll
    for (int kt = 0; kt < NKT; ++kt) {
        short8 a0 = *(const short8*)(ap + kt * 32);
        short8 a1 = *(const short8*)(ap + 16 * LDI + kt * 32);
        short8 bf[CPW];
#pragma unroll
        for (int i = 0; i < CPW; ++i)
            bf[i] = *(const short8*)(Wf + ((size_t)((wv + 8 * i) * NKT + kt) * 64 + lane) * 8);
#pragma unroll
        for (int i = 0; i < CPW; ++i) {
            acc[0][i] = __builtin_amdgcn_mfma_f32_16x16x32_bf16(bf[i], a0, acc[0][i], 0, 0, 0);
            acc[1][i] = __builtin_amdgcn_mfma_f32_16x16x32_bf16(bf[i], a1, acc[1][i], 0, 0, 0);
        }
    }
    __builtin_amdgcn_s_setprio(0);
#pragma unroll
    for (int i = 0; i < CPW; ++i) {
        int nbase = (wv + 8 * i) * 16 + quad * 4;
        if (nbase < NSTORE) {  // NSTORE % 4 == 0: group fully in or out
            float bv[4];
#pragma unroll
            for (int r = 0; r < 4; ++r)
                bv[r] = (nbase + r < NREAL) ? bias[nbase + r] : 0.f;
#pragma unroll
            for (int rt = 0; rt < 2; ++rt) {
                int row = rt * 16 + l15;
                unsigned short h[4];
#pragma unroll
                for (int r = 0; r < 4; ++r) {
                    float v = fmaxf(acc[rt][i][r] + bv[r], 0.f);
                    h[r] = (nbase + r < NREAL) ? f2bf(v) : (unsigned short)0;
                }
                u32x2 pk;
                pk[0] = (unsigned)h[0] | ((unsigned)h[1] << 16);
                pk[1] = (unsigned)h[2] | ((unsigned)h[3] << 16);
                *(u32x2*)(outL + row * LDO + nbase) = pk;  // 8B aligned
            }
        }
    }
}

// ------- fused encoder + expert chain + loss over bucketed rows, 32/block ---
// Two-buffer ping-pong: A (32x392): x -> h2 -> eh1 -> eh3
//                       B (32x264): h1 -> z -> eh2
// 512 threads = 8 waves, 8-way column split, RT=2 row-tiles per wave.
__global__ __launch_bounds__(512, 6) void fused_kernel(
    const float* __restrict__ x, const float* __restrict__ xn,
    const int* __restrict__ counts, const int* __restrict__ idxlist,
    const unsigned short* __restrict__ Wts,
    const float* __restrict__ b1, const float* __restrict__ b2,
    const float* __restrict__ b3, const float* __restrict__ eb1,
    const float* __restrict__ eb2, const float* __restrict__ eb3,
    const float* __restrict__ eb4, float* __restrict__ out) {
    int e = blockIdx.y;
    int cnt = counts[e];
    int start = blockIdx.x * ROWS;
    if (start >= cnt) return;
    int nrows = min(ROWS, cnt - start);

    __shared__ unsigned short A[ROWS * 392];
    __shared__ unsigned short B[ROWS * 264];
    __shared__ int s_idx[ROWS];
    __shared__ float s_part[8];

    int tid = threadIdx.x;
    int wv = tid >> 6, lane = tid & 63;
    const int quad = lane >> 4, l15 = lane & 15;

    if (tid < ROWS)
        s_idx[tid] = (tid < nrows) ? idxlist[e * BATCH + start + tid] : -1;
    __syncthreads();

    // stage gathered x rows -> A bf16 ld392 (196 dwords/row), zero pad k>=362
    {
        unsigned* dA = (unsigned*)A;
        for (int i = tid; i < ROWS * 196; i += 512) {
            int r = i / 196, c = i - r * 196;
            int b = s_idx[r];
            unsigned pk = 0u;
            if (c < 181 && b >= 0) {
                float2 v = *(const float2*)(x + (size_t)b * 362 + 2 * c);
                pk = (unsigned)f2bf(v.x) | ((unsigned)f2bf(v.y) << 16);
            }
            dA[i] = pk;
        }
    }
    __syncthreads();
    // enc L1: x(Kp384, A ld392) -> h1 (B ld264)
    mfma_layer<384, 256, 392, 264, 256, 256>(Wts + OFF_W1, b1, A, B, wv, lane);
    __syncthreads();
    // enc L2: h1(Kp256, B ld264) -> h2 (A ld264 region, 200 real pad 224)
    mfma_layer<256, 256, 264, 264, 200, 224>(Wts + OFF_W2, b2, B, A, wv, lane);
    __syncthreads();
    // enc L3: h2(Kp224, A ld264) -> z (B ld136, 100 real sigmoid, pad 128)
    // CPW=1 (Np=128, 8 waves): ct = wv; swapped operands like mfma_layer.
    {
        const unsigned short* W3f = Wts + OFF_W3;
        f32x4 acc3[2];
#pragma unroll
        for (int rt = 0; rt < 2; ++rt) acc3[rt] = (f32x4){0.f, 0.f, 0.f, 0.f};
        const unsigned short* ap = A + l15 * 264 + quad * 8;
        __builtin_amdgcn_s_setprio(1);
#pragma unroll
        for (int kt = 0; kt < 7; ++kt) {
            short8 a0 = *(const short8*)(ap + kt * 32);
            short8 a1 = *(const short8*)(ap + 16 * 264 + kt * 32);
            short8 bf = *(const short8*)(W3f + ((size_t)(wv * 7 + kt) * 64 + lane) * 8);
            acc3[0] = __builtin_amdgcn_mfma_f32_16x16x32_bf16(bf, a0, acc3[0], 0, 0, 0);
            acc3[1] = __builtin_amdgcn_mfma_f32_16x16x32_bf16(bf, a1, acc3[1], 0, 0, 0);
        }
        __builtin_amdgcn_s_setprio(0);
        int nbase = wv * 16 + quad * 4;  // 0..124
        float bv[4];
#pragma unroll
        for (int r = 0; r < 4; ++r)
            bv[r] = (nbase + r < 100) ? b3[nbase + r] : 0.f;
#pragma unroll
        for (int rt = 0; rt < 2; ++rt) {
            int row = rt * 16 + l15;
            unsigned short h[4];
#pragma unroll
            for (int r = 0; r < 4; ++r) {
                float s = 1.0f / (1.0f + expf(-(acc3[rt][r] + bv[r])));
                h[r] = (nbase + r < 100) ? f2bf(s) : (unsigned short)0;
            }
            u32x2 pk;
            pk[0] = (unsigned)h[0] | ((unsigned)h[1] << 16);
            pk[1] = (unsigned)h[2] | ((unsigned)h[3] << 16);
            *(u32x2*)(B + row * 136 + nbase) = pk;
        }
    }
    __syncthreads();
    // E1: z(Kp128, B ld136) -> eh1 (A ld168, 150 real pad 160)
    mfma_layer<128, 256, 136, 168, 150, 160>(Wts + OFF_E1 + (size_t)e * 32768,
                                             eb1 + e * 150, B, A, wv, lane);
    __syncthreads();
    // E2: eh1(Kp160, A ld168) -> eh2 (B ld264, 250 real pad 256)
    mfma_layer<160, 256, 168, 264, 250, 256>(Wts + OFF_E2 + (size_t)e * 40960,
                                             eb2 + e * 250, A, B, wv, lane);
    __syncthreads();
    // E3: eh2(Kp256, B ld264) -> eh3 (A ld328, 300 real pad 320)
    mfma_layer<256, 384, 264, 328, 300, 320>(Wts + OFF_E3 + (size_t)e * 98304,
                                             eb3 + e * 300, B, A, wv, lane);
    __syncthreads();

    // E4: eh3(Kp320, A ld328), Np=384 (CPW=3), loss vs (xn-x) read directly.
    // Swapped: lane holds 4 consecutive n for batch row rt*16+l15 ->
    // x/xn read as aligned float2 pairs (362 even, nbase even).
    float lacc = 0.0f;
    {
        constexpr int NKT = 10, CPW = 3;
        const unsigned short* Wf = Wts + OFF_E4 + (size_t)e * 122880;
        const float* bias4 = eb4 + (size_t)e * 362;
        f32x4 acc[2][CPW];
#pragma unroll
        for (int rt = 0; rt < 2; ++rt)
#pragma unroll
            for (int i = 0; i < CPW; ++i) acc[rt][i] = (f32x4){0.f, 0.f, 0.f, 0.f};
        const unsigned short* ap = A + l15 * 328 + quad * 8;
        __builtin_amdgcn_s_setprio(1);
#pragma unroll
        for (int kt = 0; kt < NKT; ++kt) {
            short8 a0 = *(const short8*)(ap + kt * 32);
            short8 a1 = *(const short8*)(ap + 16 * 328 + kt * 32);
            short8 bf[CPW];
#pragma unroll
            for (int i = 0; i < CPW; ++i)
                bf[i] = *(const short8*)(Wf + ((size_t)((wv + 8 * i) * NKT + kt) * 64 + lane) * 8);
#pragma unroll
            for (int i = 0; i < CPW; ++i) {
                acc[0][i] = __builtin_amdgcn_mfma_f32_16x16x32_bf16(bf[i], a0, acc[0][i], 0, 0, 0);
                acc[1][i] = __builtin_amdgcn_mfma_f32_16x16x32_bf16(bf[i], a1, acc[1][i], 0, 0, 0);
            }
        }
        __builtin_amdgcn_s_setprio(0);
        const float WC0 = 1.0f / 65536.0f;
        const float WCR = 1.0f / (361.0f * 65536.0f);
#pragma unroll
        for (int i = 0; i < CPW; ++i) {
            int nbase = (wv + 8 * i) * 16 + quad * 4;
            if (nbase < 362) {          // nbase multiple of 4 -> nbase <= 360
                bool p1 = nbase + 2 < 362;  // second pair fully valid?
                float bv0 = bias4[nbase], bv1 = bias4[nbase + 1];
                float bv2 = p1 ? bias4[nbase + 2] : 0.f;
                float bv3 = p1 ? bias4[nbase + 3] : 0.f;
                float w0 = (nbase == 0) ? WC0 : WCR;
#pragma unroll
                for (int rt = 0; rt < 2; ++rt) {
                    int b = s_idx[rt * 16 + l15];
                    if (b >= 0) {
                        const float* xp  = x  + (size_t)b * 362 + nbase;
                        const float* xnp = xn + (size_t)b * 362 + nbase;
                        float2 xa  = *(const float2*)xp;
                        float2 xna = *(const float2*)xnp;
                        float e0 = acc[rt][i][0] + bv0 - (xna.x - xa.x);
                        float e1 = acc[rt][i][1] + bv1 - (xna.y - xa.y);
                        lacc += w0 * e0 * e0 + WCR * e1 * e1;
                        if (p1) {
                            float2 xb  = *(const float2*)(xp + 2);
                            float2 xnb = *(const float2*)(xnp + 2);
                            float e2 = acc[rt][i][2] + bv2 - (xnb.x - xb.x);
                            float e3 = acc[rt][i][3] + bv3 - (xnb.y - xb.y);
                            lacc += WCR * (e2 * e2 + e3 * e3);
                        }
                    }
                }
            }
        }
    }
    // block reduction -> atomicAdd
    for (int off = 32; off; off >>= 1)
        lacc += __shfl_down(lacc, off, 64);
    if ((tid & 63) == 0) s_part[wv] = lacc;
    __syncthreads();
    if (tid == 0) {
        float s = 0.f;
#pragma unroll
        for (int i = 0; i < 8; ++i) s += s_part[i];
        atomicAdd(out, s);
    }
}

extern "C" void kernel_launch(void* const* d_in, const int* in_sizes, int n_in,
                              void* d_out, int out_size, void* d_ws, size_t ws_size,
                              hipStream_t stream) {
    const float* x   = (const float*)d_in[0];
    const float* xn  = (const float*)d_in[1];
    const int*   a   = (const int*)d_in[2];
    const float* W1  = (const float*)d_in[3];
    const float* b1  = (const float*)d_in[4];
    const float* W2  = (const float*)d_in[5];
    const float* b2  = (const float*)d_in[6];
    const float* W3  = (const float*)d_in[7];
    const float* b3  = (const float*)d_in[8];
    const float* eW1 = (const float*)d_in[9];
    const float* eb1 = (const float*)d_in[10];
    const float* eW2 = (const float*)d_in[11];
    const float* eb2 = (const float*)d_in[12];
    const float* eW3 = (const float*)d_in[13];
    const float* eb3 = (const float*)d_in[14];
    const float* eW4 = (const float*)d_in[15];
    const float* eb4 = (const float*)d_in[16];

    char* ws = (char*)d_ws;
    int* counts           = (int*)ws;
    int* idxlist          = (int*)(ws + WS_IDX_OFF);
    unsigned short* Wts   = (unsigned short*)(ws + WS_WT_OFF);

    hipMemsetAsync(d_out, 0, sizeof(float), stream);

    repack_kernel<<<dim3(128, 15), 256, 0, stream>>>(W1, W2, W3, eW1, eW2, eW3,
                                                     eW4, Wts, counts);
    bucket_kernel<<<BATCH / 1024, 1024, 0, stream>>>(a, counts, idxlist);
    fused_kernel<<<dim3((BATCH + ROWS - 1) / ROWS, 3), 512, 0, stream>>>(
        x, xn, counts, idxlist, Wts, b1, b2, b3, eb1, eb2, eb3, eb4, (float*)d_out);
}